// Round 3
// baseline (84.987 us; speedup 1.0000x reference)
//
#include <hip/hip_runtime.h>
#include <math.h>

// PartialChamferLoss: B=2, N=8192, M=32768, S=4096.
// d2 = |x|^2 + |y|^2 - 2 x.y ; min over M per query ; mean(sqrt).
// R11: revert R10 (8-wave probe landed on the "already-at-floor" branch:
// +1.9us from doubled per-step overhead; main is issue-bound at ~8-11us).
// Back to R9 shape (R=16, 4 waves/SIMD, best 82.4us) + structural change:
// eliminate the memset dispatch AND cross-block atomicMin. The block's 4
// waves share qg and cover 4 CONSECUTIVE tch -> intra-block LDS min-combine
// gives one value per (query, tchgrp-of-4), written by exactly ONE block:
// plain float stores, no init, no atomics. wsmin = 8192 x 8 floats (256KB,
// L2-hot). finish min-reduces 8 slots/query (2x float4, coalesced).
// Ledger: -memset node (~1.3us) -1 graph gap (~2us) -262k atomicMin,
// +~1.5-2us finish read. Predict 82.4 -> 79-81us. If >=82: structural
// floor -> ROOFLINE.
// Kept from R9: float4 staging into named regs, AoS float4 query ring,
// ds_bpermute traveling min, #pragma unroll 1, per-block query gather.
typedef float vf2 __attribute__((ext_vector_type(2)));
typedef float vf4 __attribute__((ext_vector_type(4)));

constexpr int B = 2;
constexpr int N = 8192;
constexpr int M = 32768;
constexpr int S = 4096;
constexpr int QTOT = B * S;          // 8192 queries
constexpr int R = 16;                // targets per lane (no spill at 16)
constexpr int WT = 64 * R;           // 1024 targets per wave
constexpr int TCH = M / WT;          // 32 target chunks per batch
constexpr int TG = TCH / 4;          // 8 tch-groups (one per block)
constexpr int QG = S / 64;           // 64 query groups per batch
constexpr int WAVES = B * TCH * QG;  // 4096 waves
constexpr int BLOCKS = WAVES / 4;    // 1024 blocks x 256 threads

#define DECLP(j) vf2 T0_##j, T1_##j, T2_##j, TY_##j;

// Load 4 consecutive targets (12 contiguous floats = 3 float4) for this
// lane and repack into two vf2 pairs pA=(t0,t1), pB=(t2,t3).
// Row r covers targets [256r, 256r+256); lane l owns 256r+4l .. +3.
#define LOADQUAD(r, pA, pB)                                               \
  {                                                                       \
    vf4 u0 = gt[192 * (r) + 3 * lane];                                    \
    vf4 u1 = gt[192 * (r) + 3 * lane + 1];                                \
    vf4 u2 = gt[192 * (r) + 3 * lane + 2];                                \
    T0_##pA = vf2{u0.x, u0.w};                                            \
    T1_##pA = vf2{u0.y, u1.x};                                            \
    T2_##pA = vf2{u0.z, u1.y};                                            \
    TY_##pA = vf2{fmaf(u0.x, u0.x, fmaf(u0.y, u0.y, u0.z * u0.z)),        \
                  fmaf(u0.w, u0.w, fmaf(u1.x, u1.x, u1.y * u1.y))};       \
    T0_##pB = vf2{u1.z, u2.y};                                            \
    T1_##pB = vf2{u1.w, u2.z};                                            \
    T2_##pB = vf2{u2.x, u2.w};                                            \
    TY_##pB = vf2{fmaf(u1.z, u1.z, fmaf(u1.w, u1.w, u2.x * u2.x)),        \
                  fmaf(u2.y, u2.y, fmaf(u2.z, u2.z, u2.w * u2.w))};       \
  }

#define PAIRC(j, acc)                                                    \
  {                                                                      \
    vf2 s = __builtin_elementwise_fma(Q0, T0_##j, TY_##j);               \
    s = __builtin_elementwise_fma(Q1, T1_##j, s);                        \
    s = __builtin_elementwise_fma(Q2, T2_##j, s);                        \
    acc = fminf(fminf(s.x, s.y), acc); /* v_min3_f32 */                  \
  }

__global__ __launch_bounds__(256, 4) void chamfer_main(
    const float* __restrict__ pred, const float* __restrict__ target,
    const int* __restrict__ idx, float* __restrict__ wsmin) {
  __shared__ vf4 qv[64];      // {-2x, -2y, -2z, |x|^2} per query
  __shared__ float cmb[4][64];  // per-wave chunk-min, combined post-loop
  const int lane = threadIdx.x & 63;
  const int w = blockIdx.x * 4 + (threadIdx.x >> 6);  // 0..4095
  const int b = w >> 11;            // uniform per block
  const int rem = w & 2047;
  const int tch = rem & (TCH - 1);  // block covers {4k..4k+3}
  const int qg = rem >> 5;          // uniform per block (4 | TCH)

  // Gather this block's query group directly from pred[idx] (L2-hot).
  if (threadIdx.x < 64) {
    int s = qg * 64 + threadIdx.x;
    int i = idx[s];
    const float* p = pred + ((size_t)b * N + (size_t)i) * 3;
    float x = p[0], y = p[1], z = p[2];
    qv[threadIdx.x] =
        vf4{-2.0f * x, -2.0f * y, -2.0f * z, fmaf(x, x, fmaf(y, y, z * z))};
  }

  // Stage this lane's 16 targets (4 rows x 4 consecutive targets) into
  // NAMED registers via 12 float4 loads.
  const float* tb = target + ((size_t)b * M + (size_t)tch * WT) * 3;
  const vf4* gt = (const vf4*)tb;
  DECLP(0) DECLP(1) DECLP(2) DECLP(3) DECLP(4) DECLP(5) DECLP(6) DECLP(7)
  LOADQUAD(0, 0, 1) LOADQUAD(1, 2, 3) LOADQUAD(2, 4, 5) LOADQUAD(3, 6, 7)
  __syncthreads();

  const vf4 qh = qv[lane];                // own query record (.w = |x|^2)
  const int rot = ((lane + 1) & 63) * 4;  // bpermute byte-addr: pull lane+1
  float mm = INFINITY;                    // traveling min of (|y|^2 - 2x.y)
  int qoff = lane;
  vf4 qc = qh;

#pragma unroll 1  // keep the 32 vf2 target regs' live ranges tight
  for (int step = 0; step < 64; ++step) {
    // Prefetch next query (single ds_read_b128 hides under 8-pair compute).
    const int qn = (qoff + 1) & 63;
    vf4 nq = qv[qn];
    const vf2 Q0 = vf2{qc.x, qc.x};
    const vf2 Q1 = vf2{qc.y, qc.y};
    const vf2 Q2 = vf2{qc.z, qc.z};
    float m0 = INFINITY, m1 = INFINITY;
    PAIRC(0, m0) PAIRC(1, m1) PAIRC(2, m0) PAIRC(3, m1)
    PAIRC(4, m0) PAIRC(5, m1) PAIRC(6, m0) PAIRC(7, m1)
    // Incoming traveling min (prev step's bpermute) consumed only here.
    mm = fminf(mm, fminf(m0, m1));
    mm = __int_as_float(__builtin_amdgcn_ds_bpermute(rot, __float_as_int(mm)));
    qc = nq;
    qoff = qn;
  }
  // After 64 rotations the own query's complete chunk-min is back home.
  // Intra-block combine: 4 waves (consecutive tch) -> one slot per query.
  cmb[threadIdx.x >> 6][lane] = fmaxf(qh.w + mm, 0.0f);
  __syncthreads();
  if (threadIdx.x < 64) {
    float v = fminf(fminf(cmb[0][threadIdx.x], cmb[1][threadIdx.x]),
                    fminf(cmb[2][threadIdx.x], cmb[3][threadIdx.x]));
    const int q = b * S + qg * 64 + threadIdx.x;
    wsmin[q * TG + (tch >> 2)] = v;  // sole writer of this slot: plain store
  }
}

__global__ __launch_bounds__(1024) void chamfer_finish(
    const float* __restrict__ wsmin, float* __restrict__ out) {
  __shared__ float red[16];
  const vf4* wm = (const vf4*)wsmin;  // 2 vf4 per query (TG=8 slots)
  float sum = 0.0f;
#pragma unroll
  for (int i = 0; i < QTOT / 1024; ++i) {  // 8 queries per thread
    int q = threadIdx.x + i * 1024;
    vf4 a = wm[2 * q];
    vf4 c = wm[2 * q + 1];
    float m = fminf(fminf(fminf(a.x, a.y), fminf(a.z, a.w)),
                    fminf(fminf(c.x, c.y), fminf(c.z, c.w)));
    sum += sqrtf(m);
  }
#pragma unroll
  for (int off = 32; off > 0; off >>= 1)
    sum += __shfl_down(sum, off, 64);
  int wv = threadIdx.x >> 6;
  if ((threadIdx.x & 63) == 0) red[wv] = sum;
  __syncthreads();
  if (threadIdx.x == 0) {
    float t = 0.0f;
#pragma unroll
    for (int i = 0; i < 16; ++i) t += red[i];
    out[0] = t / (float)QTOT;
  }
}

extern "C" void kernel_launch(void* const* d_in, const int* in_sizes, int n_in,
                              void* d_out, int out_size, void* d_ws, size_t ws_size,
                              hipStream_t stream) {
  const float* pred = (const float*)d_in[0];
  const float* target = (const float*)d_in[1];
  const int* idx = (const int*)d_in[2];
  float* wsmin = (float*)d_ws;

  chamfer_main<<<BLOCKS, 256, 0, stream>>>(pred, target, idx, wsmin);
  chamfer_finish<<<1, 1024, 0, stream>>>(wsmin, (float*)d_out);
}

// Round 4
// 82.294 us; speedup vs baseline: 1.0327x; 1.0327x over previous
//
#include <hip/hip_runtime.h>
#include <math.h>

// PartialChamferLoss: B=2, N=8192, M=32768, S=4096.
// d2 = |x|^2 + |y|^2 - 2 x.y ; min over M per query ; mean(sqrt).
// R12: terminal revert to the best harness-verified config (R8, 82.44us).
// Session evidence that this is the structural floor:
//  - R9 (float4 staging, AoS query ring): exactly neutral -> memory pipes
//    off the critical path.
//  - R10 (8 waves/SIMD occupancy probe): +1.9us, matching the predicted
//    instruction-count overhead branch -> main is VALU-issue-bound
//    (~8-11us), not latency/stall-bound.
//  - R11 (no-memset, atomic-free per-block stores + LDS combine): +2.5us
//    -> dispatch-structure ledger falsified; graph nodes are cheap, the
//    combine/finish-traffic additions are not.
//  - Timed region is dominated by the harness 268MB ws re-poison fill
//    (~40us @ 84% achievable HBM, itself at ITS roofline) + harness
//    restore dispatches. Controllable kernels are at their VALU floor.
typedef float vf2 __attribute__((ext_vector_type(2)));

constexpr int B = 2;
constexpr int N = 8192;
constexpr int M = 32768;
constexpr int S = 4096;
constexpr int QTOT = B * S;          // 8192 queries
constexpr int R = 16;                // targets per lane (no spill at 16)
constexpr int WT = 64 * R;           // 1024 targets per wave
constexpr int TCH = M / WT;          // 32 target chunks per batch
constexpr int QG = S / 64;           // 64 query groups per batch
constexpr int WAVES = B * TCH * QG;  // 4096 waves
constexpr int BLOCKS = WAVES / 4;    // 1024 blocks x 256 threads

#define DECLP(j) vf2 T0_##j, T1_##j, T2_##j, TY_##j;
#define LOADP(j)                                                         \
  {                                                                      \
    int mA = (2 * j) * 64 + lane, mB = (2 * j + 1) * 64 + lane;          \
    float ax = tb[3 * mA], ay = tb[3 * mA + 1], az = tb[3 * mA + 2];     \
    float bx = tb[3 * mB], by = tb[3 * mB + 1], bz = tb[3 * mB + 2];     \
    T0_##j = vf2{ax, bx};                                                \
    T1_##j = vf2{ay, by};                                                \
    T2_##j = vf2{az, bz};                                                \
    TY_##j = vf2{fmaf(ax, ax, fmaf(ay, ay, az * az)),                    \
                 fmaf(bx, bx, fmaf(by, by, bz * bz))};                   \
  }
#define PAIRC(j, acc)                                                    \
  {                                                                      \
    vf2 s = __builtin_elementwise_fma(Q0, T0_##j, TY_##j);               \
    s = __builtin_elementwise_fma(Q1, T1_##j, s);                        \
    s = __builtin_elementwise_fma(Q2, T2_##j, s);                        \
    acc = fminf(fminf(s.x, s.y), acc); /* v_min3_f32 */                  \
  }

__global__ __launch_bounds__(256, 4) void chamfer_main(
    const float* __restrict__ pred, const float* __restrict__ target,
    const int* __restrict__ idx, unsigned* __restrict__ wsmin) {
  __shared__ float qs0[64], qs1[64], qs2[64], qw[64];  // SoA query records
  const int lane = threadIdx.x & 63;
  const int w = blockIdx.x * 4 + (threadIdx.x >> 6);  // 0..4095
  const int b = w >> 11;
  const int rem = w & 2047;
  const int tch = rem & (TCH - 1);  // varies across block's 4 waves
  const int qg = rem >> 5;          // uniform across block (4 | TCH)

  // Gather this block's query group directly from pred[idx] (L2-hot).
  if (threadIdx.x < 64) {
    int s = qg * 64 + threadIdx.x;
    int i = idx[s];
    const float* p = pred + ((size_t)b * N + (size_t)i) * 3;
    float x = p[0], y = p[1], z = p[2];
    qs0[threadIdx.x] = -2.0f * x;
    qs1[threadIdx.x] = -2.0f * y;
    qs2[threadIdx.x] = -2.0f * z;
    qw[threadIdx.x] = x * x + y * y + z * z;
  }

  // Stage this lane's 16 targets into NAMED registers (8 float2-pairs).
  const float* tb = target + ((size_t)b * M + (size_t)tch * WT) * 3;
  DECLP(0) DECLP(1) DECLP(2) DECLP(3) DECLP(4) DECLP(5) DECLP(6) DECLP(7)
  LOADP(0) LOADP(1) LOADP(2) LOADP(3) LOADP(4) LOADP(5) LOADP(6) LOADP(7)
  __syncthreads();

  const float qx2_home = qw[lane];        // own |x|^2, applied at the end
  const int rot = ((lane + 1) & 63) * 4;  // bpermute byte-addr: pull lane+1
  float mm = INFINITY;                    // traveling min of (|y|^2 - 2x.y)
  int qoff = lane;
  float q0 = qs0[qoff], q1 = qs1[qoff], q2 = qs2[qoff];

#pragma unroll 1  // keep the 32 vf2 target regs' live ranges tight
  for (int step = 0; step < 64; ++step) {
    // Prefetch next query (LDS latency hides under the 8-pair compute).
    int qn = (qoff + 1) & 63;
    float n0 = qs0[qn], n1 = qs1[qn], n2 = qs2[qn];
    vf2 Q0 = vf2{q0, q0}, Q1 = vf2{q1, q1}, Q2 = vf2{q2, q2};
    float m0 = INFINITY, m1 = INFINITY;
    PAIRC(0, m0) PAIRC(1, m1) PAIRC(2, m0) PAIRC(3, m1)
    PAIRC(4, m0) PAIRC(5, m1) PAIRC(6, m0) PAIRC(7, m1)
    // Incoming traveling min (prev step's bpermute) consumed only here.
    mm = fminf(mm, fminf(m0, m1));
    mm = __int_as_float(__builtin_amdgcn_ds_bpermute(rot, __float_as_int(mm)));
    q0 = n0; q1 = n1; q2 = n2; qoff = qn;
  }
  // After 64 rotations the own query's complete chunk-min is back home.
  const int q = b * S + qg * 64 + lane;
  atomicMin(&wsmin[q], __float_as_uint(fmaxf(qx2_home + mm, 0.0f)));
}

__global__ __launch_bounds__(1024) void chamfer_finish(
    const unsigned* __restrict__ wsmin, float* __restrict__ out) {
  __shared__ float red[16];
  float sum = 0.0f;
#pragma unroll
  for (int i = 0; i < QTOT / 1024; ++i)
    sum += sqrtf(__uint_as_float(wsmin[threadIdx.x + i * 1024]));
#pragma unroll
  for (int off = 32; off > 0; off >>= 1)
    sum += __shfl_down(sum, off, 64);
  int wv = threadIdx.x >> 6;
  if ((threadIdx.x & 63) == 0) red[wv] = sum;
  __syncthreads();
  if (threadIdx.x == 0) {
    float t = 0.0f;
#pragma unroll
    for (int i = 0; i < 16; ++i) t += red[i];
    out[0] = t / (float)QTOT;
  }
}

extern "C" void kernel_launch(void* const* d_in, const int* in_sizes, int n_in,
                              void* d_out, int out_size, void* d_ws, size_t ws_size,
                              hipStream_t stream) {
  const float* pred = (const float*)d_in[0];
  const float* target = (const float*)d_in[1];
  const int* idx = (const int*)d_in[2];
  unsigned* wsmin = (unsigned*)d_ws;

  hipMemsetAsync(wsmin, 0xFF, QTOT * sizeof(unsigned), stream);
  chamfer_main<<<BLOCKS, 256, 0, stream>>>(pred, target, idx, wsmin);
  chamfer_finish<<<1, 1024, 0, stream>>>(wsmin, (float*)d_out);
}